// Round 9
// baseline (61.899 us; speedup 1.0000x reference)
//
#include <hip/hip_runtime.h>
#include <hip/hip_bf16.h>
#include <math.h>

#define NH 1024
#define SEQ 1024
#define BATCH 2
#define NHEAD 16
#define DHEAD 64

typedef __attribute__((ext_vector_type(8))) short short8;
typedef __attribute__((ext_vector_type(4))) float f32x4;
typedef __attribute__((ext_vector_type(2))) float f32x2;

__device__ __forceinline__ unsigned short f2bf(float f) {
    unsigned u = __builtin_bit_cast(unsigned, f);
    unsigned r = 0x7FFFu + ((u >> 16) & 1u);
    u += r;
    return (unsigned short)(u >> 16);
}
__device__ __forceinline__ unsigned pk_bf2(float lo, float hi) {
    return (unsigned)f2bf(lo) | ((unsigned)f2bf(hi) << 16);
}
__device__ __forceinline__ unsigned cvtpk_bf16(float lo, float hi) {
    unsigned r;
    asm("v_cvt_pk_bf16_f32 %0, %1, %2" : "=v"(r) : "v"(lo), "v"(hi));
    return r;
}

typedef __attribute__((address_space(1))) const unsigned int as1_uint;
typedef __attribute__((address_space(3))) unsigned int as3_uint;
__device__ __forceinline__ void gload16(const void* g, void* l) {
    __builtin_amdgcn_global_load_lds((as1_uint*)g, (as3_uint*)l, 16, 0, 0);
}

// ---------------- Kernel 1: LayerNorm per row -> bf16 xn ----------------
__global__ __launch_bounds__(256) void k_ln(const float* __restrict__ x,
                                            const float* __restrict__ g,
                                            const float* __restrict__ b,
                                            unsigned short* __restrict__ xnb) {
    int row = blockIdx.x;
    int t = threadIdx.x;
    const float4* xr = (const float4*)(x + (size_t)row * NH);
    float4 xv = xr[t];
    float s  = xv.x + xv.y + xv.z + xv.w;
    float ss = xv.x*xv.x + xv.y*xv.y + xv.z*xv.z + xv.w*xv.w;
    for (int off = 32; off > 0; off >>= 1) {
        s  += __shfl_down(s, off);
        ss += __shfl_down(ss, off);
    }
    __shared__ float ls[4], lss[4];
    int wid = t >> 6;
    if ((t & 63) == 0) { ls[wid] = s; lss[wid] = ss; }
    __syncthreads();
    s  = ls[0] + ls[1] + ls[2] + ls[3];
    ss = lss[0] + lss[1] + lss[2] + lss[3];
    float mu  = s * (1.0f / NH);
    float var = ss * (1.0f / NH) - mu * mu;
    float rstd = rsqrtf(var + 1e-5f);
    float4 gv = ((const float4*)g)[t];
    float4 bv = ((const float4*)b)[t];
    float o0 = (xv.x - mu) * rstd * gv.x + bv.x;
    float o1 = (xv.y - mu) * rstd * gv.y + bv.y;
    float o2 = (xv.z - mu) * rstd * gv.z + bv.z;
    float o3 = (xv.w - mu) * rstd * gv.w + bv.w;
    uint2 u;
    u.x = pk_bf2(o0, o1);
    u.y = pk_bf2(o2, o3);
    *(uint2*)(xnb + (size_t)row * NH + t * 4) = u;
}

// ---------------- Kernel 2: fused prep: WvT, WqkT, maskf ----------------
__global__ __launch_bounds__(256) void k_prep(const float* __restrict__ Wv,
                                              const float* __restrict__ Wq,
                                              const float* __restrict__ Wk,
                                              const float* __restrict__ mask,
                                              unsigned short* __restrict__ WvT,
                                              unsigned short* __restrict__ WqkT,
                                              float* __restrict__ maskf) {
    __shared__ float T[64][65];
    int bid = blockIdx.x;
    int t = threadIdx.x;
    if (bid < 256) {
        int k0 = (bid >> 4) * 64, n0 = (bid & 15) * 64;
        int row = t >> 2, c4 = t & 3;
#pragma unroll
        for (int s = 0; s < 4; ++s) {
            float4 v = *(const float4*)(Wv + (size_t)(k0 + row) * NH + n0 + c4 * 16 + s * 4);
            *(float4*)&T[row][c4 * 16 + s * 4] = v;
        }
        __syncthreads();
        unsigned short tmp[16] __attribute__((aligned(16)));
#pragma unroll
        for (int s = 0; s < 16; ++s) tmp[s] = f2bf(T[c4 * 16 + s][row]);
        unsigned short* dst = WvT + (size_t)(n0 + row) * NH + k0 + c4 * 16;
        *(short8*)dst = *(const short8*)&tmp[0];
        *(short8*)(dst + 8) = *(const short8*)&tmp[8];
    } else if (bid < 512) {
        int i = (bid - 256) * 256 + t;   // 65536 entries
        int n = i >> 10, k = i & 1023;
        float v = (n < 16) ? Wq[k * 16 + n] : (n < 32 ? Wk[k * 16 + (n - 16)] : 0.0f);
        WqkT[i] = f2bf(v);
    } else {
        int i = (bid - 512) * 256 + t;
        maskf[i] = (1.0f - mask[i]) * 0.044194173824159216f * 0.69314718055994531f;
    }
}

// ---------------- Kernel 3: MFMA GEMM xn @ [Wv | Wq|Wk] -> vt bf16 + qT/kT f32, BK=128 ----------------
__global__ __launch_bounds__(256) void k_vmfma(const unsigned short* __restrict__ Abf,
                                               const unsigned short* __restrict__ WvT,
                                               const unsigned short* __restrict__ WqkT,
                                               const float* __restrict__ bias,
                                               const float* __restrict__ bq,
                                               const float* __restrict__ bk,
                                               unsigned short* __restrict__ vt,
                                               float* __restrict__ qT,
                                               float* __restrict__ kT) {
    __shared__ unsigned short lds[2][16384]; // per buf: A 64x128 @0 (8192), B 64x128 @8192
    int t = threadIdx.x, w = t >> 6, lane = t & 63, g = lane >> 4, r = lane & 15;
    int nt_ = blockIdx.x % 17, mt = blockIdx.x / 17;
    int i0 = mt * 64, n0 = nt_ * 64;
    const unsigned short* Bsrc = (nt_ < 16) ? (WvT + (size_t)n0 * NH) : WqkT;

    f32x4 acc[2][2];
#pragma unroll
    for (int a = 0; a < 2; ++a)
#pragma unroll
        for (int c = 0; c < 2; ++c) acc[a][c] = (f32x4)(0.0f);

    auto stage = [&](int buf, int k0) {
#pragma unroll
        for (int i = 0; i < 4; ++i) {
            int o = i * 4096 + t * 16;            // byte offset in 16KB A region
            int rr = o >> 8, cb = o & 255;
            int sc = (cb ^ ((rr & 15) << 4)) >> 1;
            gload16(Abf + (size_t)(i0 + rr) * NH + k0 + sc, &lds[buf][o >> 1]);
        }
#pragma unroll
        for (int i = 0; i < 4; ++i) {
            int o = i * 4096 + t * 16;
            int rr = o >> 8, cb = o & 255;
            int sc = (cb ^ ((rr & 15) << 4)) >> 1;
            gload16(Bsrc + (size_t)rr * NH + k0 + sc, &lds[buf][8192 + (o >> 1)]);
        }
    };

    int mbase = (w >> 1) * 32, nbase = (w & 1) * 32;

    auto compute = [&](int buf) {
        const unsigned short* As = lds[buf];
        const unsigned short* Bs = lds[buf] + 8192;
#pragma unroll
        for (int ks = 0; ks < 4; ++ks) {
            int kbyte = ks * 64 + g * 16;
            short8 af[2], bfm[2];
#pragma unroll
            for (int mf = 0; mf < 2; ++mf) {
                int row = mbase + mf * 16 + r;
                int kb = kbyte ^ ((row & 15) << 4);
                af[mf] = *(const short8*)(As + ((row * 256 + kb) >> 1));
            }
#pragma unroll
            for (int nf = 0; nf < 2; ++nf) {
                int rowB = nbase + nf * 16 + r;
                int kb = kbyte ^ ((rowB & 15) << 4);
                bfm[nf] = *(const short8*)(Bs + ((rowB * 256 + kb) >> 1));
            }
#pragma unroll
            for (int mf = 0; mf < 2; ++mf)
#pragma unroll
                for (int nf = 0; nf < 2; ++nf)
                    acc[mf][nf] = __builtin_amdgcn_mfma_f32_16x16x32_bf16(af[mf], bfm[nf], acc[mf][nf], 0, 0, 0);
        }
    };

    stage(0, 0);
    __syncthreads();
    int cur = 0;
#pragma unroll 1
    for (int kt = 0; kt < 7; ++kt) {
        stage(cur ^ 1, (kt + 1) * 128);
        compute(cur);
        __syncthreads();
        cur ^= 1;
    }
    compute(cur);

    if (nt_ < 16) {
        unsigned short (*tsm)[72] = (unsigned short(*)[72])&lds[0][0];
#pragma unroll
        for (int nf = 0; nf < 2; ++nf) {
            float bv = bias[n0 + nbase + nf * 16 + r];
#pragma unroll
            for (int mf = 0; mf < 2; ++mf)
#pragma unroll
                for (int j = 0; j < 4; ++j)
                    tsm[nbase + nf * 16 + r][mbase + mf * 16 + g * 4 + j] = f2bf(acc[mf][nf][j] + bv);
        }
        __syncthreads();
        int b = mt >> 4;
        int jc0 = (mt & 15) * 64;
        int d = t >> 2, jb = (t & 3) * 16;
        unsigned short* dst = vt + ((size_t)((b * 16 + nt_) * 64 + d)) * 1024 + jc0 + jb;
        *(short8*)dst = *(const short8*)&tsm[d][jb];
        *(short8*)(dst + 8) = *(const short8*)&tsm[d][jb + 8];
    } else {
#pragma unroll
        for (int nf = 0; nf < 2; ++nf) {
            int n = nbase + nf * 16 + r;
            if (n < 32) {
                float bb = (n < 16) ? bq[n] : bk[n - 16];
                float* dstp = (n < 16) ? (qT + n * 2048) : (kT + (n - 16) * 2048);
#pragma unroll
                for (int mf = 0; mf < 2; ++mf)
#pragma unroll
                    for (int j = 0; j < 4; ++j)
                        dstp[i0 + mbase + mf * 16 + g * 4 + j] = acc[mf][nf][j] + bb;
            }
        }
    }
}

// ---------------- Kernel 4: fused scores (packed f32x2) + MFMA PV ----------------
__global__ __launch_bounds__(256, 4) void k_attn(const float* __restrict__ qT,
                                                 const float* __restrict__ kT,
                                                 const unsigned short* __restrict__ vt,
                                                 const float* __restrict__ x,
                                                 const float* __restrict__ maskf,
                                                 const float* __restrict__ angle,
                                                 const float* __restrict__ zfp,
                                                 float* __restrict__ out) {
    int bid = blockIdx.x;
    int lb = (bid & 7) * 128 + (bid >> 3);
    int qt = lb & 31;
    int h = (lb >> 5) & 15;
    int b = lb >> 9;
    int t = threadIdx.x;
    int w = t >> 6, lane = t & 63, g = lane >> 4, r = lane & 15;
    int i0 = qt * 32;

    __shared__ float red[4][3][32][20];

    float ang = angle[h];
    float cs = cosf(ang), sn = sinf(ang);
    float c1 = cs - sn, nc2 = -(cs + sn);
    float zf = zfp[0];
    const float L2E = 1.4426950408889634f;

    const float* qcol = qT + h * 2048 + b * 1024;
    const float* kcol = kT + h * 2048 + b * 1024;
    const float* mrow = maskf + b * 1024;
    const unsigned short* vhead = vt + ((size_t)(b * 16 + h)) * 64 * 1024;

    float qv0 = qcol[i0 + r];
    float qv1 = qcol[i0 + 16 + r];
    f32x2 c1q = {c1 * qv0, c1 * qv1};
    f32x2 snq = {sn * qv0, sn * qv1};

    f32x4 acc[2][4];
#pragma unroll
    for (int m = 0; m < 2; ++m)
#pragma unroll
        for (int nb = 0; nb < 4; ++nb) acc[m][nb] = (f32x4)(0.0f);

    int jbase = w * 256 + g * 8;

    short8 bfr[2][4];
    float4 kv4[2][2], ff4[2][2];
#pragma unroll
    for (int nb = 0; nb < 4; ++nb)
        bfr[0][nb] = *(const short8*)(vhead + (size_t)(nb * 16 + r) * 1024 + jbase);
    kv4[0][0] = *(const float4*)(kcol + jbase);
    kv4[0][1] = *(const float4*)(kcol + jbase + 4);
    ff4[0][0] = *(const float4*)(mrow + jbase);
    ff4[0][1] = *(const float4*)(mrow + jbase + 4);

#pragma unroll 2
    for (int it = 0; it < 8; ++it) {
        int cur = it & 1, nxt = cur ^ 1;
        if (it < 7) {
            int jn = jbase + (it + 1) * 32;
#pragma unroll
            for (int nb = 0; nb < 4; ++nb)
                bfr[nxt][nb] = *(const short8*)(vhead + (size_t)(nb * 16 + r) * 1024 + jn);
            kv4[nxt][0] = *(const float4*)(kcol + jn);
            kv4[nxt][1] = *(const float4*)(kcol + jn + 4);
            ff4[nxt][0] = *(const float4*)(mrow + jn);
            ff4[nxt][1] = *(const float4*)(mrow + jn + 4);
        }
        float kk[8] = {kv4[cur][0].x, kv4[cur][0].y, kv4[cur][0].z, kv4[cur][0].w,
                       kv4[cur][1].x, kv4[cur][1].y, kv4[cur][1].z, kv4[cur][1].w};
        float ff[8] = {ff4[cur][0].x, ff4[cur][0].y, ff4[cur][0].z, ff4[cur][0].w,
                       ff4[cur][1].x, ff4[cur][1].y, ff4[cur][1].z, ff4[cur][1].w};

        unsigned a0[4], a1[4];
#pragma unroll
        for (int p = 0; p < 4; ++p) {
            float sa[2], sb[2];
#pragma unroll
            for (int q2 = 0; q2 < 2; ++q2) {
                float kv = kk[p * 2 + q2];
                float f  = ff[p * 2 + q2];
                float ck = nc2 * kv;
                float ik = cs * kv;
                f32x2 dd = c1q + ck;
                f32x2 im = snq + ik;
                f32x2 tt = dd * (-L2E);
                f32x2 e  = {__builtin_amdgcn_exp2f(tt.x), __builtin_amdgcn_exp2f(tt.y)};
                f32x2 den = e + 1.0f;
                f32x2 sg  = {__builtin_amdgcn_rcpf(den.x), __builtin_amdgcn_rcpf(den.y)};
                f32x2 comp = __builtin_elementwise_fma(dd, sg, im);
                f32x2 uu = comp * L2E;
                f32x2 ee = {__builtin_amdgcn_exp2f(uu.x), __builtin_amdgcn_exp2f(uu.y)};
                f32x2 vv = ee + 1.0f;
                f32x2 lg = {__builtin_amdgcn_logf(vv.x), __builtin_amdgcn_logf(vv.y)};
                f32x2 s2 = lg * f;
                sa[q2] = s2.x;
                sb[q2] = s2.y;
            }
            a0[p] = cvtpk_bf16(sa[0], sa[1]);
            a1[p] = cvtpk_bf16(sb[0], sb[1]);
        }
        unsigned av0[4] = {a0[0], a0[1], a0[2], a0[3]};
        unsigned av1[4] = {a1[0], a1[1], a1[2], a1[3]};
        short8 af0 = *(short8*)av0;
        short8 af1 = *(short8*)av1;

#pragma unroll
        for (int nb = 0; nb < 4; ++nb) {
            acc[0][nb] = __builtin_amdgcn_mfma_f32_16x16x32_bf16(af0, bfr[cur][nb], acc[0][nb], 0, 0, 0);
            acc[1][nb] = __builtin_amdgcn_mfma_f32_16x16x32_bf16(af1, bfr[cur][nb], acc[1][nb], 0, 0, 0);
        }
    }

    // cross-wave reduce: wave w owns nb==w
#pragma unroll
    for (int nb = 0; nb < 4; ++nb) {
        if (nb != w) {
            int idx = w - (w > nb ? 1 : 0);
#pragma unroll
            for (int m = 0; m < 2; ++m)
#pragma unroll
                for (int jj = 0; jj < 4; ++jj)
                    red[nb][idx][m * 16 + g * 4 + jj][r] = acc[m][nb][jj];
        }
    }
    __syncthreads();

#pragma unroll
    for (int m = 0; m < 2; ++m)
#pragma unroll
        for (int jj = 0; jj < 4; ++jj) {
            int lrow = m * 16 + g * 4 + jj;
            float c = acc[m][w][jj] + red[w][0][lrow][r]
                                    + red[w][1][lrow][r]
                                    + red[w][2][lrow][r];
            float gl = 0.5f * c * (1.0f + erff(c * 0.70710678118654752f));
            size_t base = ((size_t)(b * 1024 + i0 + lrow)) * 1024 + h * 64 + w * 16 + r;
            out[base] = x[base] + gl * zf;
        }
}

extern "C" void kernel_launch(void* const* d_in, const int* in_sizes, int n_in,
                              void* d_out, int out_size, void* d_ws, size_t ws_size,
                              hipStream_t stream) {
    const float* x      = (const float*)d_in[0];
    const float* mask   = (const float*)d_in[1];
    const float* Wq     = (const float*)d_in[2];
    const float* bq     = (const float*)d_in[3];
    const float* Wk     = (const float*)d_in[4];
    const float* bk     = (const float*)d_in[5];
    const float* Wv     = (const float*)d_in[6];
    const float* bv     = (const float*)d_in[7];
    const float* ln_g   = (const float*)d_in[8];
    const float* ln_b   = (const float*)d_in[9];
    const float* zf     = (const float*)d_in[10];
    const float* angle  = (const float*)d_in[11];
    float* out = (float*)d_out;

    unsigned short* xnb  = (unsigned short*)d_ws;   // 2M shorts
    unsigned short* vt   = xnb + 2097152;           // 2M shorts
    unsigned short* WvT  = vt + 2097152;            // 1M shorts
    unsigned short* WqkT = WvT + 1048576;           // 64K shorts
    float* qT    = (float*)(WqkT + 65536);          // 32K f32
    float* kT    = qT + 32768;                      // 32K f32
    float* maskf = kT + 32768;                      // 2K f32

    k_prep<<<520, 256, 0, stream>>>(Wv, Wq, Wk, mask, WvT, WqkT, maskf);
    k_ln<<<BATCH * SEQ, 256, 0, stream>>>(x, ln_g, ln_b, xnb);
    k_vmfma<<<32 * 17, 256, 0, stream>>>(xnb, WvT, WqkT, bv, bq, bk, vt, qT, kT);
    k_attn<<<BATCH * NHEAD * (SEQ / 32), 256, 0, stream>>>(qT, kT, vt, x, maskf, angle, zf, out);
}